// Round 1
// baseline (543.076 us; speedup 1.0000x reference)
//
#include <hip/hip_runtime.h>
#include <stdint.h>

// Problem constants (fixed by the reference setup)
#define L_TOK 16384
#define H_HEADS 8
#define D_DIM 128
#define N_EXP 4
#define ROW4 256            // (H*D)/4 float4 per token row

// d_out layout (float32 elements, outputs concatenated in return order)
#define O_Q   0ull
#define O_K   33554432ull
#define O_V   67108864ull
#define O_GK  100663296ull
#define O_BE  100925440ull
#define O_EO  101187584ull
#define O_MW  101253120ull
#define O_OF  101318656ull
#define O_SZ  101318673ull
#define O_GS  101318689ull

// ---------------- Kernel 1: per-token softmax + top-2 ----------------
__global__ __launch_bounds__(256) void topk_kernel(
    const float4* __restrict__ e4,
    float* __restrict__ out,
    uint32_t* __restrict__ expPacked,
    float2* __restrict__ vals)
{
    int t = blockIdx.x * 256 + threadIdx.x;
    if (t >= L_TOK) return;
    float4 ev = e4[t];
    float f[4] = {ev.x, ev.y, ev.z, ev.w};

    // top-2 on raw logits (softmax is monotonic; ties -> lower index, matching lax.top_k)
    int e0 = 0; float b0 = f[0];
#pragma unroll
    for (int n = 1; n < 4; ++n) if (f[n] > b0) { b0 = f[n]; e0 = n; }
    int e1 = -1; float b1 = -1e30f;
#pragma unroll
    for (int n = 0; n < 4; ++n) if (n != e0 && f[n] > b1) { b1 = f[n]; e1 = n; }

    // softmax (max-subtracted)
    float s = 0.f; float ex[4];
#pragma unroll
    for (int n = 0; n < 4; ++n) { ex[n] = __expf(f[n] - b0); s += ex[n]; }
    float inv = 1.f / s;
    float4 ef = make_float4(ex[0]*inv, ex[1]*inv, ex[2]*inv, ex[3]*inv);

    ((float4*)(out + O_EO))[t] = ef;
    float4 mw;
    mw.x = (e0 == 0 || e1 == 0) ? 1.f : 0.f;
    mw.y = (e0 == 1 || e1 == 1) ? 1.f : 0.f;
    mw.z = (e0 == 2 || e1 == 2) ? 1.f : 0.f;
    mw.w = (e0 == 3 || e1 == 3) ? 1.f : 0.f;
    ((float4*)(out + O_MW))[t] = mw;

    expPacked[t] = (uint32_t)e0 | ((uint32_t)e1 << 8);
    float v0 = (e0 == 0) ? ef.x : (e0 == 1) ? ef.y : (e0 == 2) ? ef.z : ef.w;
    float v1 = (e1 == 0) ? ef.x : (e1 == 1) ? ef.y : (e1 == 2) ? ef.z : ef.w;
    vals[t] = make_float2(v0, v1);
}

// ---------------- Kernel 2: single-block packed prefix scan ----------------
// P01 lane layout: expert0 in bits[15:0], expert1 in bits[31:16]; P23 same for experts 2,3.
// Per-expert totals <= 2*L? No: <= L (each token picks an expert at most once) < 65536. Safe.
__global__ __launch_bounds__(1024) void scan_kernel(
    const uint32_t* __restrict__ expPacked,
    const int* __restrict__ cu,
    uint32_t* __restrict__ P01, uint32_t* __restrict__ P23,
    int* __restrict__ base,
    float* __restrict__ out)
{
    const int tid = threadIdx.x;           // 1024 threads, 16 tokens each
    uint32_t inc01[16], inc23[16];
    uint32_t s01 = 0, s23 = 0;
    const uint4* ep4 = (const uint4*)expPacked + tid * 4;
#pragma unroll
    for (int c = 0; c < 4; ++c) {
        uint4 w = ep4[c];
        uint32_t es[4] = {w.x, w.y, w.z, w.w};
#pragma unroll
        for (int j2 = 0; j2 < 4; ++j2) {
            uint32_t ep = es[j2];
            int e0 = ep & 0xff, e1 = (ep >> 8) & 0xff;
            uint32_t a01 = 0, a23 = 0;
            a01 += (e0 == 0) ? 1u : 0u;  a01 += (e0 == 1) ? (1u << 16) : 0u;
            a23 += (e0 == 2) ? 1u : 0u;  a23 += (e0 == 3) ? (1u << 16) : 0u;
            a01 += (e1 == 0) ? 1u : 0u;  a01 += (e1 == 1) ? (1u << 16) : 0u;
            a23 += (e1 == 2) ? 1u : 0u;  a23 += (e1 == 3) ? (1u << 16) : 0u;
            int j = c * 4 + j2;
            inc01[j] = a01; inc23[j] = a23;
            s01 += a01; s23 += a23;
        }
    }
    __shared__ uint32_t sm01[1024], sm23[1024];
    sm01[tid] = s01; sm23[tid] = s23;
    __syncthreads();
    for (int off = 1; off < 1024; off <<= 1) {
        uint32_t a = 0, b = 0;
        if (tid >= off) { a = sm01[tid - off]; b = sm23[tid - off]; }
        __syncthreads();
        sm01[tid] += a; sm23[tid] += b;
        __syncthreads();
    }
    uint32_t r01 = tid ? sm01[tid - 1] : 0u;
    uint32_t r23 = tid ? sm23[tid - 1] : 0u;
#pragma unroll
    for (int j = 0; j < 16; ++j) {
        int t = tid * 16 + j;
        P01[t] = r01; P23[t] = r23;
        r01 += inc01[j]; r23 += inc23[j];
    }
    if (tid == 1023) { P01[L_TOK] = r01; P23[L_TOK] = r23; }
    __syncthreads();   // global writes visible within workgroup (same CU)

    if (tid == 0) {
        out[O_OF + 0] = 0.f;
        int off = 0;
        for (int s = 0; s < 4; ++s) {
            uint32_t pa0 = P01[cu[s]], pa1 = P01[cu[s + 1]];
            uint32_t pb0 = P23[cu[s]], pb1 = P23[cu[s + 1]];
            int cnt[4], pst[4];
            cnt[0] = (int)((pa1 & 0xffffu) - (pa0 & 0xffffu)); pst[0] = (int)(pa0 & 0xffffu);
            cnt[1] = (int)((pa1 >> 16)     - (pa0 >> 16));     pst[1] = (int)(pa0 >> 16);
            cnt[2] = (int)((pb1 & 0xffffu) - (pb0 & 0xffffu)); pst[2] = (int)(pb0 & 0xffffu);
            cnt[3] = (int)((pb1 >> 16)     - (pb0 >> 16));     pst[3] = (int)(pb0 >> 16);
            for (int e = 0; e < 4; ++e) {
                base[s * 4 + e] = off - pst[e];
                out[O_SZ + s * 4 + e] = (float)cnt[e];
                off += cnt[e];
                out[O_OF + s * 4 + e + 1] = (float)off;
            }
        }
    }
}

// ---------------- Kernel 3: gather/scatter rows (1 block per token) ----------------
__device__ __forceinline__ int pick16(int e, uint32_t p01, uint32_t p23) {
    uint32_t p = (e < 2) ? p01 : p23;
    return (e & 1) ? (int)(p >> 16) : (int)(p & 0xffffu);
}

__global__ __launch_bounds__(256) void scatter_kernel(
    const float4* __restrict__ q4, const float4* __restrict__ k4, const float4* __restrict__ v4,
    const float* __restrict__ gk, const float* __restrict__ beta,
    const int* __restrict__ cu,
    const uint32_t* __restrict__ expPacked, const float2* __restrict__ vals,
    const uint32_t* __restrict__ P01, const uint32_t* __restrict__ P23,
    const int* __restrict__ base,
    float* __restrict__ out)
{
    const int t = blockIdx.x;
    const int tid = threadIdx.x;

    uint32_t ep = expPacked[t];
    int e0 = ep & 0xff, e1 = (ep >> 8) & 0xff;
    float2 vv = vals[t];
    int s = (t >= cu[1]) + (t >= cu[2]) + (t >= cu[3]);
    uint32_t p01 = P01[t], p23 = P23[t];
    size_t d0 = (size_t)(base[s * 4 + e0] + pick16(e0, p01, p23));
    size_t d1 = (size_t)(base[s * 4 + e1] + pick16(e1, p01, p23));

    float4 qv = q4[(size_t)t * ROW4 + tid];
    float4 kv = k4[(size_t)t * ROW4 + tid];
    float4 vr = v4[(size_t)t * ROW4 + tid];

    float4* oq = (float4*)(out + O_Q);
    float4* ok = (float4*)(out + O_K);
    float4* ov = (float4*)(out + O_V);
    float a = vv.x, b = vv.y;

    oq[d0 * ROW4 + tid] = make_float4(qv.x * a, qv.y * a, qv.z * a, qv.w * a);
    oq[d1 * ROW4 + tid] = make_float4(qv.x * b, qv.y * b, qv.z * b, qv.w * b);
    ok[d0 * ROW4 + tid] = make_float4(kv.x * a, kv.y * a, kv.z * a, kv.w * a);
    ok[d1 * ROW4 + tid] = make_float4(kv.x * b, kv.y * b, kv.z * b, kv.w * b);
    ov[d0 * ROW4 + tid] = vr;
    ov[d1 * ROW4 + tid] = vr;

    if (tid < 8) {
        float g = gk[t * 8 + tid];
        out[O_GK + d0 * 8 + tid] = g;
        out[O_GK + d1 * 8 + tid] = g;
        float bt = beta[t * 8 + tid];
        out[O_BE + d0 * 8 + tid] = bt;
        out[O_BE + d1 * 8 + tid] = bt;
    } else if (tid == 8) {
        out[O_GS + d0] = (float)t;
        out[O_GS + d1] = (float)t;
    }
}

extern "C" void kernel_launch(void* const* d_in, const int* in_sizes, int n_in,
                              void* d_out, int out_size, void* d_ws, size_t ws_size,
                              hipStream_t stream)
{
    const float* q    = (const float*)d_in[0];
    const float* k    = (const float*)d_in[1];
    const float* v    = (const float*)d_in[2];
    const float* gk   = (const float*)d_in[3];
    const float* beta = (const float*)d_in[4];
    const float* e    = (const float*)d_in[5];
    const int*   cu   = (const int*)d_in[6];
    float* out = (float*)d_out;

    char* ws = (char*)d_ws;
    uint32_t* expPacked = (uint32_t*)(ws);                       // L * 4 B
    float2*   vals      = (float2*)(ws + 65536);                 // L * 8 B
    uint32_t* P01       = (uint32_t*)(ws + 65536 + 131072);      // (L+16) * 4 B
    uint32_t* P23       = (uint32_t*)(ws + 65536 + 131072 + 65600);
    int*      base      = (int*)(ws + 65536 + 131072 + 65600 + 65600);

    topk_kernel<<<L_TOK / 256, 256, 0, stream>>>((const float4*)e, out, expPacked, vals);
    scan_kernel<<<1, 1024, 0, stream>>>(expPacked, cu, P01, P23, base, out);
    scatter_kernel<<<L_TOK, 256, 0, stream>>>((const float4*)q, (const float4*)k, (const float4*)v,
                                              gk, beta, cu, expPacked, vals, P01, P23, base, out);
}